// Round 5
// baseline (83.240 us; speedup 1.0000x reference)
//
#include <hip/hip_runtime.h>

#define MAX_SPIKE 100000.0f

constexpr int BATCH  = 128;
constexpr int NIN    = 1024;
constexpr int MOUT   = 512;
constexpr int T      = 256;           // scan: 4 waves per block
constexpr int NWAVE  = 4;             // n-segments
constexpr int SEGLEN = NIN / NWAVE;   // 256
constexpr int CPB    = 64;            // columns per block (one per lane)
constexpr int CH     = 8;             // prefetch chunk
constexpr int ST     = 512;           // sort threads (8 waves)

typedef unsigned long long u64;

// ---------------- kernel 1: per-row stable argsort (hybrid bitonic) --------
// T=512: thread (wv,l) owns elements i0 = wv*128+l and i1 = i0+64.
// j<=32 stages: __shfl_xor (no barriers). j==64: intra-thread. j>=128: LDS.
__global__ __launch_bounds__(ST) void snn_sort_kernel(const float* __restrict__ x,
                                                      float* __restrict__ xs_g,
                                                      int* __restrict__ ro_g) {
    __shared__ u64 keys[NIN];
    const int tid = threadIdx.x;
    const int b   = blockIdx.x;
    const int wv  = tid >> 6;
    const int l   = tid & 63;
    const int i0  = wv * 128 + l;     // bit6 == 0 always
    const int i1  = i0 + 64;

    // key = (float_bits << 32) | index: x >= 0 so uint order == float order;
    // index low bits make keys distinct -> deterministic == stable argsort.
    u64 e0 = ((u64)__float_as_uint(x[b * NIN + i0]) << 32) | (unsigned)i0;
    u64 e1 = ((u64)__float_as_uint(x[b * NIN + i1]) << 32) | (unsigned)i1;

    // compare-exchange with shfl partner (j <= 32): lower lane keeps min iff asc
    auto CE_SHFL = [&](u64& e, int idx, int k, int j) {
        u64 p = __shfl_xor(e, j, 64);
        bool lower   = ((l & j) == 0);
        bool asc     = ((idx & k) == 0);
        bool takeMin = (lower == asc);
        bool pLess   = (p < e);
        e = (pLess == takeMin) ? p : e;
    };
    // j == 64: pair (i0, i1) lives in this thread's two registers
    auto CE_J64 = [&](int k) {
        bool asc = ((i0 & k) == 0);
        bool sw  = asc ? (e0 > e1) : (e0 < e1);
        if (sw) { u64 t = e0; e0 = e1; e1 = t; }
    };

    // k = 2 .. 64: fully in-register
    for (int k = 2; k <= 64; k <<= 1)
        for (int j = k >> 1; j >= 1; j >>= 1) { CE_SHFL(e0, i0, k, j); CE_SHFL(e1, i1, k, j); }
    // k = 128: j=64 intra-thread, then j=32..1
    CE_J64(128);
    for (int j = 32; j >= 1; j >>= 1) { CE_SHFL(e0, i0, 128, j); CE_SHFL(e1, i1, 128, j); }

    // k = 256, 512, 1024: j>=128 via LDS, rest in-register
    for (int k = 256; k <= NIN; k <<= 1) {
        keys[i0] = e0; keys[i1] = e1;
        __syncthreads();
        for (int j = k >> 1; j >= 128; j >>= 1) {
            int idx  = ((tid & ~(j - 1)) << 1) | (tid & (j - 1));
            int part = idx | j;
            u64 a = keys[idx], c = keys[part];
            bool asc = ((idx & k) == 0);
            if (asc ? (a > c) : (a < c)) { keys[idx] = c; keys[part] = a; }
            __syncthreads();
        }
        e0 = keys[i0]; e1 = keys[i1];
        CE_J64(k);
        for (int j = 32; j >= 1; j >>= 1) { CE_SHFL(e0, i0, k, j); CE_SHFL(e1, i1, k, j); }
    }

    xs_g[b * (NIN + 1) + i0] = __uint_as_float((unsigned)(e0 >> 32));
    xs_g[b * (NIN + 1) + i1] = __uint_as_float((unsigned)(e1 >> 32));
    ro_g[b * NIN + i0] = (int)(unsigned)(e0 & 0xFFFFFFFFull) * (MOUT * 4);  // byte off
    ro_g[b * NIN + i1] = (int)(unsigned)(e1 & 0xFFFFFFFFull) * (MOUT * 4);
    if (tid == 0) xs_g[b * (NIN + 1) + NIN] = MAX_SPIKE;
}

// ---------------- kernel 2: segmented scan, screened division --------------
__global__ __launch_bounds__(T) void snn_scan_kernel(const float* __restrict__ w,
                                                     const float* __restrict__ xs_g,
                                                     const int* __restrict__ ro_g,
                                                     float* __restrict__ out) {
    // Running cumsums + exact path must match numpy f32: no FMA contraction.
    #pragma clang fp contract(off)

    __shared__ float bestsh[NWAVE][CPB];

    const int tid  = threadIdx.x;
    const int b    = blockIdx.x >> 3;
    const int cg   = blockIdx.x & 7;
    const int wave = tid >> 6;
    const int lane = tid & 63;
    const int seg  = (wave + blockIdx.x) & (NWAVE - 1);   // straggler swizzle
    const unsigned mo4 = (unsigned)(cg * CPB + lane) * 4u;

    const int*   __restrict__ ro_p = ro_g + b * NIN;       // wave-uniform reads
    const float* __restrict__ xs_p = xs_g + b * (NIN + 1); // wave-uniform reads
    const char*  wb = (const char*)w;

    float wcum = 0.0f, wicum = 0.0f, best = MAX_SPIKE;
    float wA[CH], wB[CH];

#define LOADC(dst, base_) { const int bb_ = (base_); _Pragma("unroll") \
    for (int u = 0; u < CH; ++u) { \
        unsigned off = (unsigned)ro_p[bb_ + u] + mo4; \
        dst[u] = *(const float*)(wb + off); } }

    // ---- phase 1: exact sequential prefix over [0, seg*SEGLEN); no screens
    // (reference yields MAX only via min; prefix holds no candidates we keep).
    const int npre = seg * SEGLEN;
    if (npre > 0) {
        LOADC(wA, 0);
        for (int c = 0; c < npre / CH; c += 2) {
            LOADC(wB, (c + 1) * CH);
            #pragma unroll
            for (int u = 0; u < CH; ++u) {
                float ww = wA[u];
                wcum  = wcum + ww;
                wicum = wicum + ww * xs_p[c * CH + u];   // round mul, then add
            }
            if ((c + 2) * CH < npre) LOADC(wA, (c + 2) * CH);
            #pragma unroll
            for (int u = 0; u < CH; ++u) {
                float ww = wB[u];
                wcum  = wcum + ww;
                wicum = wicum + ww * xs_p[(c + 1) * CH + u];
            }
        }
    }

    // ---- phase 2: candidate scan on own segment.
    // Cheap mode while all lanes have wcum < 1 (=> reference emits MAX_SPIKE
    // exactly, no candidate possible). The chunk where any lane crosses is
    // REPLAYED from a snapshot in screen mode -- exact equivalence.
    // Screen skips only when exact path provably rejects (1-ulp-safe margins);
    // borderline lanes take the exact IEEE-division reference path.
    const int n0 = seg * SEGLEN;
    bool scr = (__any((int)(wcum >= 1.0f)) != 0);
    float xprev = xs_p[n0];

#define PROCESS(wreg, nb_) { const int nb = (nb_); \
    if (!scr) { \
        float wc0 = wcum, wi0 = wicum; \
        _Pragma("unroll") \
        for (int u = 0; u < CH; ++u) { \
            float ww = wreg[u]; \
            wcum  = wcum + ww; \
            wicum = wicum + ww * xs_p[nb + u]; \
        } \
        if (__any((int)(wcum >= 1.0f))) { \
            wcum = wc0; wicum = wi0; scr = true; xprev = xs_p[nb]; \
        } \
    } \
    if (scr) { \
        _Pragma("unroll") \
        for (int u = 0; u < CH; ++u) { \
            float ww = wreg[u]; \
            float xv = xprev; \
            float xl = xs_p[nb + u + 1]; \
            wcum  = wcum + ww; \
            wicum = wicum + ww * xv; \
            float d = fmaxf(wcum - 1.0f, 1e-10f); \
            bool pot = (wcum >= 1.0f) && (wicum >= (xv * d) * (1.0f - 8e-7f)) \
                                      && (wicum <= (xl * d) * (1.0f + 8e-7f)); \
            if (pot) { \
                float q = wicum / d;          /* IEEE f32 div (matches np) */ \
                float cand = (q < xv || q > xl) ? MAX_SPIKE : q; \
                best = fminf(best, cand); \
            } \
            xprev = xl; \
        } \
    } }

    LOADC(wA, n0);
    constexpr int NCH2 = SEGLEN / CH;        // 32 (even)
    for (int c = 0; c < NCH2; c += 2) {
        LOADC(wB, n0 + (c + 1) * CH);
        PROCESS(wA, n0 + c * CH);
        if (c + 2 < NCH2) LOADC(wA, n0 + (c + 2) * CH);
        PROCESS(wB, n0 + (c + 1) * CH);
    }
#undef PROCESS
#undef LOADC

    bestsh[wave][lane] = best;
    __syncthreads();
    if (tid < CPB) {
        float r0 = fminf(fminf(bestsh[0][tid], bestsh[1][tid]),
                         fminf(bestsh[2][tid], bestsh[3][tid]));
        out[b * MOUT + cg * CPB + tid] = r0;
    }
}

// ---------------- fallback: fused kernel (if ws too small) -----------------
__global__ __launch_bounds__(T) void snn_fc_fused(const float* __restrict__ x,
                                                  const float* __restrict__ w,
                                                  float* __restrict__ out) {
    #pragma clang fp contract(off)
    __shared__ u64 keys[NIN];
    __shared__ float xs[NIN + 1];
    __shared__ int   roff[NIN];
    __shared__ float bestsh[NWAVE][CPB];

    const int tid  = threadIdx.x;
    const int b    = blockIdx.x >> 3;
    const int cg   = blockIdx.x & 7;
    const int wave = tid >> 6;
    const int lane = tid & 63;
    const int mo   = cg * CPB + lane;

    for (int i = tid; i < NIN; i += T) {
        unsigned int bits = __float_as_uint(x[b * NIN + i]);
        keys[i] = ((u64)bits << 32) | (unsigned int)i;
    }
    __syncthreads();
    for (int k = 2; k <= NIN; k <<= 1)
        for (int j = k >> 1; j > 0; j >>= 1) {
            #pragma unroll
            for (int r = 0; r < NIN / T; ++r) {
                int i = tid + r * T, ixj = i ^ j;
                if (ixj > i) {
                    u64 a = keys[i], c2 = keys[ixj];
                    bool asc = ((i & k) == 0);
                    if ((a > c2) == asc) { keys[i] = c2; keys[ixj] = a; }
                }
            }
            __syncthreads();
        }
    for (int i = tid; i < NIN; i += T) {
        u64 kk = keys[i];
        xs[i]   = __uint_as_float((unsigned int)(kk >> 32));
        roff[i] = (int)(kk & 0xFFFFFFFFull) * MOUT;
    }
    if (tid == 0) xs[NIN] = MAX_SPIKE;
    __syncthreads();

    const float* __restrict__ wcol = w + mo;
    float wcum = 0.0f, wicum = 0.0f, best = MAX_SPIKE;

    for (int n = 0; n < wave * SEGLEN; ++n) {
        float ww = wcol[roff[n]];
        wcum = wcum + ww;
        wicum = wicum + ww * xs[n];
    }
    const int n0 = wave * SEGLEN;
    float xprev = xs[n0];
    for (int n = n0; n < n0 + SEGLEN; ++n) {
        float ww = wcol[roff[n]];
        float xv = xprev, xl = xs[n + 1];
        wcum = wcum + ww;
        wicum = wicum + ww * xv;
        float d = fminf(fmaxf(wcum - 1.0f, 1e-10f), 1e10f);
        float q = wicum / d;
        float cand = (wcum < 1.0f || q < xv || q > xl) ? MAX_SPIKE : q;
        best = fminf(best, cand);
        xprev = xl;
    }
    bestsh[wave][lane] = best;
    __syncthreads();
    if (tid < CPB) {
        float r0 = fminf(fminf(bestsh[0][tid], bestsh[1][tid]),
                         fminf(bestsh[2][tid], bestsh[3][tid]));
        out[b * MOUT + cg * CPB + tid] = r0;
    }
}

extern "C" void kernel_launch(void* const* d_in, const int* in_sizes, int n_in,
                              void* d_out, int out_size, void* d_ws, size_t ws_size,
                              hipStream_t stream) {
    (void)in_sizes; (void)n_in; (void)out_size;
    const float* x = (const float*)d_in[0];
    const float* w = (const float*)d_in[1];
    float* out = (float*)d_out;

    const size_t xs_bytes = (size_t)BATCH * (NIN + 1) * sizeof(float);
    const size_t ro_bytes = (size_t)BATCH * NIN * sizeof(int);

    if (ws_size >= xs_bytes + ro_bytes) {
        float* xs_g = (float*)d_ws;
        int*   ro_g = (int*)((char*)d_ws + xs_bytes);
        hipLaunchKernelGGL(snn_sort_kernel, dim3(BATCH), dim3(ST), 0, stream,
                           x, xs_g, ro_g);
        hipLaunchKernelGGL(snn_scan_kernel, dim3(BATCH * (MOUT / CPB)), dim3(T),
                           0, stream, w, xs_g, ro_g, out);
    } else {
        hipLaunchKernelGGL(snn_fc_fused, dim3(BATCH * (MOUT / CPB)), dim3(T),
                           0, stream, x, w, out);
    }
}

// Round 6
// 80.604 us; speedup vs baseline: 1.0327x; 1.0327x over previous
//
#include <hip/hip_runtime.h>

#define MAX_SPIKE 100000.0f

constexpr int BATCH  = 128;
constexpr int NIN    = 1024;
constexpr int MOUT   = 512;
constexpr int T      = 256;           // scan: 4 waves per block
constexpr int NWAVE  = 4;             // n-segments
constexpr int SEGLEN = NIN / NWAVE;   // 256
constexpr int CPB    = 64;            // columns per block (one per lane)
constexpr int CH     = 16;            // chunk (prefetch granularity)
constexpr int ST     = 512;           // sort threads (8 waves)

typedef unsigned long long u64;

// ---------------- kernel 1: per-row stable argsort (hybrid bitonic) --------
// Emits packed pairs: pair[n] = (ro_bytes << 32) | float_bits(xs), where
// ro_bytes = sorted_index * MOUT * 4 (byte offset into a weight row).
__global__ __launch_bounds__(ST) void snn_sort_kernel(const float* __restrict__ x,
                                                      u64* __restrict__ pair_g) {
    __shared__ u64 keys[NIN];
    const int tid = threadIdx.x;
    const int b   = blockIdx.x;
    const int wv  = tid >> 6;
    const int l   = tid & 63;
    const int i0  = wv * 128 + l;     // bit6 == 0 always
    const int i1  = i0 + 64;

    // key = (float_bits << 32) | index: x >= 0 so uint order == float order;
    // index low bits make keys distinct -> deterministic == stable argsort.
    u64 e0 = ((u64)__float_as_uint(x[b * NIN + i0]) << 32) | (unsigned)i0;
    u64 e1 = ((u64)__float_as_uint(x[b * NIN + i1]) << 32) | (unsigned)i1;

    auto CE_SHFL = [&](u64& e, int idx, int k, int j) {
        u64 p = __shfl_xor(e, j, 64);
        bool lower   = ((l & j) == 0);
        bool asc     = ((idx & k) == 0);
        bool takeMin = (lower == asc);
        bool pLess   = (p < e);
        e = (pLess == takeMin) ? p : e;
    };
    auto CE_J64 = [&](int k) {
        bool asc = ((i0 & k) == 0);
        bool sw  = asc ? (e0 > e1) : (e0 < e1);
        if (sw) { u64 t = e0; e0 = e1; e1 = t; }
    };

    for (int k = 2; k <= 64; k <<= 1)
        for (int j = k >> 1; j >= 1; j >>= 1) { CE_SHFL(e0, i0, k, j); CE_SHFL(e1, i1, k, j); }
    CE_J64(128);
    for (int j = 32; j >= 1; j >>= 1) { CE_SHFL(e0, i0, 128, j); CE_SHFL(e1, i1, 128, j); }

    for (int k = 256; k <= NIN; k <<= 1) {
        keys[i0] = e0; keys[i1] = e1;
        __syncthreads();
        for (int j = k >> 1; j >= 128; j >>= 1) {
            int idx  = ((tid & ~(j - 1)) << 1) | (tid & (j - 1));
            int part = idx | j;
            u64 a = keys[idx], c = keys[part];
            bool asc = ((idx & k) == 0);
            if (asc ? (a > c) : (a < c)) { keys[idx] = c; keys[part] = a; }
            __syncthreads();
        }
        e0 = keys[i0]; e1 = keys[i1];
        CE_J64(k);
        for (int j = 32; j >= 1; j >>= 1) { CE_SHFL(e0, i0, k, j); CE_SHFL(e1, i1, k, j); }
    }

    u64* pg = pair_g + b * (NIN + 1);
    {
        unsigned ro0 = (unsigned)(e0 & 0xFFFFFFFFull) * (MOUT * 4);
        unsigned ro1 = (unsigned)(e1 & 0xFFFFFFFFull) * (MOUT * 4);
        pg[i0] = ((u64)ro0 << 32) | (unsigned)(e0 >> 32);
        pg[i1] = ((u64)ro1 << 32) | (unsigned)(e1 >> 32);
    }
    if (tid == 0) pg[NIN] = ((u64)0 << 32) | __float_as_uint(MAX_SPIKE);
}

// ---------------- kernel 2: segmented scan, screened division --------------
__global__ __launch_bounds__(T) void snn_scan_kernel(const float* __restrict__ w,
                                                     const u64* __restrict__ pair_g,
                                                     float* __restrict__ out) {
    // Running cumsums + exact path must match numpy f32: no FMA contraction.
    #pragma clang fp contract(off)

    __shared__ u64 pr[NIN + 1];
    __shared__ float bestsh[NWAVE][CPB];

    const int tid  = threadIdx.x;
    const int b    = blockIdx.x >> 3;
    const int cg   = blockIdx.x & 7;
    const int wave = tid >> 6;
    const int lane = tid & 63;
    const int seg  = (wave + blockIdx.x) & (NWAVE - 1);   // straggler swizzle
    const unsigned mo4 = (unsigned)(cg * CPB + lane) * 4u;

    const u64* __restrict__ pg = pair_g + b * (NIN + 1);
    for (int i = tid; i < NIN + 1; i += T) pr[i] = pg[i];
    __syncthreads();

    const char* wb = (const char*)w;
    float wcum = 0.0f, wicum = 0.0f, best = MAX_SPIKE;
    float xsA[CH], xsB[CH], wA[CH], wB[CH];

    // One broadcast ds_read_b64 per element gives {xs, weight-row byte offset}.
#define LOADC(XS, WR, base_) { const int bb_ = (base_); _Pragma("unroll") \
    for (int u = 0; u < CH; ++u) { \
        u64 p = pr[bb_ + u]; \
        XS[u] = __uint_as_float((unsigned)p); \
        WR[u] = *(const float*)(wb + ((unsigned)(p >> 32) + mo4)); } }

    // ---- phase 1: exact sequential prefix over [0, seg*SEGLEN); no screens.
    const int npre = seg * SEGLEN;
    if (npre > 0) {
        LOADC(xsA, wA, 0);
        for (int c = 0; c < npre / CH; c += 2) {
            LOADC(xsB, wB, (c + 1) * CH);
            #pragma unroll
            for (int u = 0; u < CH; ++u) {
                float ww = wA[u];
                wcum  = wcum + ww;
                wicum = wicum + ww * xsA[u];   // round mul, then add (np order)
            }
            if ((c + 2) * CH < npre) LOADC(xsA, wA, (c + 2) * CH);
            #pragma unroll
            for (int u = 0; u < CH; ++u) {
                float ww = wB[u];
                wcum  = wcum + ww;
                wicum = wicum + ww * xsB[u];
            }
        }
    }

    // ---- phase 2: candidate scan on own segment.
    // Cheap mode while ALL lanes have wcum < 1: weights >= 0 so wcum is
    // monotone; every element in such a chunk has wcum < 1 => reference emits
    // MAX_SPIKE exactly. The chunk where any lane crosses is REPLAYED from a
    // 2-register snapshot in screen mode (identical add order => bit-exact).
    // Screen skips only when the exact path provably rejects (1-ulp margins);
    // borderline lanes take the exact IEEE-division reference path.
    const int n0 = seg * SEGLEN;
    bool scr = (__any((int)(wcum >= 1.0f)) != 0);

#define PROCESS(XS, WR, xnext_) { \
    if (!scr) { \
        float wc0 = wcum, wi0 = wicum; \
        _Pragma("unroll") \
        for (int u = 0; u < CH; ++u) { \
            float ww = WR[u]; \
            wcum  = wcum + ww; \
            wicum = wicum + ww * XS[u]; \
        } \
        if (__any((int)(wcum >= 1.0f))) { wcum = wc0; wicum = wi0; scr = true; } \
    } \
    if (scr) { \
        _Pragma("unroll") \
        for (int u = 0; u < CH; ++u) { \
            float ww = WR[u]; \
            float xv = XS[u]; \
            float xl = (u < CH - 1) ? XS[u + 1] : (xnext_); \
            wcum  = wcum + ww; \
            wicum = wicum + ww * xv; \
            float d = fmaxf(wcum - 1.0f, 1e-10f); /* 1e10 clip never binds: wcum<=~4.3 */ \
            bool pot = (wcum >= 1.0f) && (wicum >= (xv * d) * (1.0f - 8e-7f)) \
                                      && (wicum <= (xl * d) * (1.0f + 8e-7f)); \
            if (pot) { \
                float q = wicum / d;            /* IEEE f32 div (matches np) */ \
                float cand = (q < xv || q > xl) ? MAX_SPIKE : q; \
                best = fminf(best, cand); \
            } \
        } \
    } }

    LOADC(xsA, wA, n0);
    constexpr int NCH2 = SEGLEN / CH;        // 16 (even)
    for (int c = 0; c < NCH2; c += 2) {
        LOADC(xsB, wB, n0 + (c + 1) * CH);
        PROCESS(xsA, wA, xsB[0]);
        const bool more = (c + 2 < NCH2);
        if (more) LOADC(xsA, wA, n0 + (c + 2) * CH);
        float xnB = more ? xsA[0] : __uint_as_float((unsigned)pr[n0 + SEGLEN]);
        PROCESS(xsB, wB, xnB);
    }
#undef PROCESS
#undef LOADC

    bestsh[wave][lane] = best;
    __syncthreads();
    if (tid < CPB) {
        float r0 = fminf(fminf(bestsh[0][tid], bestsh[1][tid]),
                         fminf(bestsh[2][tid], bestsh[3][tid]));
        out[b * MOUT + cg * CPB + tid] = r0;
    }
}

// ---------------- fallback: fused kernel (if ws too small) -----------------
__global__ __launch_bounds__(T) void snn_fc_fused(const float* __restrict__ x,
                                                  const float* __restrict__ w,
                                                  float* __restrict__ out) {
    #pragma clang fp contract(off)
    __shared__ u64 keys[NIN];
    __shared__ float xs[NIN + 1];
    __shared__ int   roff[NIN];
    __shared__ float bestsh[NWAVE][CPB];

    const int tid  = threadIdx.x;
    const int b    = blockIdx.x >> 3;
    const int cg   = blockIdx.x & 7;
    const int wave = tid >> 6;
    const int lane = tid & 63;
    const int mo   = cg * CPB + lane;

    for (int i = tid; i < NIN; i += T) {
        unsigned int bits = __float_as_uint(x[b * NIN + i]);
        keys[i] = ((u64)bits << 32) | (unsigned int)i;
    }
    __syncthreads();
    for (int k = 2; k <= NIN; k <<= 1)
        for (int j = k >> 1; j > 0; j >>= 1) {
            #pragma unroll
            for (int r = 0; r < NIN / T; ++r) {
                int i = tid + r * T, ixj = i ^ j;
                if (ixj > i) {
                    u64 a = keys[i], c2 = keys[ixj];
                    bool asc = ((i & k) == 0);
                    if ((a > c2) == asc) { keys[i] = c2; keys[ixj] = a; }
                }
            }
            __syncthreads();
        }
    for (int i = tid; i < NIN; i += T) {
        u64 kk = keys[i];
        xs[i]   = __uint_as_float((unsigned int)(kk >> 32));
        roff[i] = (int)(kk & 0xFFFFFFFFull) * MOUT;
    }
    if (tid == 0) xs[NIN] = MAX_SPIKE;
    __syncthreads();

    const float* __restrict__ wcol = w + mo;
    float wcum = 0.0f, wicum = 0.0f, best = MAX_SPIKE;

    for (int n = 0; n < wave * SEGLEN; ++n) {
        float ww = wcol[roff[n]];
        wcum = wcum + ww;
        wicum = wicum + ww * xs[n];
    }
    const int n0 = wave * SEGLEN;
    float xprev = xs[n0];
    for (int n = n0; n < n0 + SEGLEN; ++n) {
        float ww = wcol[roff[n]];
        float xv = xprev, xl = xs[n + 1];
        wcum = wcum + ww;
        wicum = wicum + ww * xv;
        float d = fminf(fmaxf(wcum - 1.0f, 1e-10f), 1e10f);
        float q = wicum / d;
        float cand = (wcum < 1.0f || q < xv || q > xl) ? MAX_SPIKE : q;
        best = fminf(best, cand);
        xprev = xl;
    }
    bestsh[wave][lane] = best;
    __syncthreads();
    if (tid < CPB) {
        float r0 = fminf(fminf(bestsh[0][tid], bestsh[1][tid]),
                         fminf(bestsh[2][tid], bestsh[3][tid]));
        out[b * MOUT + cg * CPB + tid] = r0;
    }
}

extern "C" void kernel_launch(void* const* d_in, const int* in_sizes, int n_in,
                              void* d_out, int out_size, void* d_ws, size_t ws_size,
                              hipStream_t stream) {
    (void)in_sizes; (void)n_in; (void)out_size;
    const float* x = (const float*)d_in[0];
    const float* w = (const float*)d_in[1];
    float* out = (float*)d_out;

    const size_t pair_bytes = (size_t)BATCH * (NIN + 1) * sizeof(u64);

    if (ws_size >= pair_bytes) {
        u64* pair_g = (u64*)d_ws;
        hipLaunchKernelGGL(snn_sort_kernel, dim3(BATCH), dim3(ST), 0, stream,
                           x, pair_g);
        hipLaunchKernelGGL(snn_scan_kernel, dim3(BATCH * (MOUT / CPB)), dim3(T),
                           0, stream, w, pair_g, out);
    } else {
        hipLaunchKernelGGL(snn_fc_fused, dim3(BATCH * (MOUT / CPB)), dim3(T),
                           0, stream, x, w, out);
    }
}

// Round 7
// 68.862 us; speedup vs baseline: 1.2088x; 1.1705x over previous
//
#include <hip/hip_runtime.h>

#define MAX_SPIKE 100000.0f

constexpr int BATCH  = 128;
constexpr int NIN    = 1024;
constexpr int MOUT   = 512;
constexpr int T      = 512;           // scan: 8 waves per block
constexpr int NWAVE  = 8;             // n-segments
constexpr int SEGLEN = NIN / NWAVE;   // 128
constexpr int CPB    = 64;            // columns per block (one per lane)
constexpr int CH     = 8;             // prefetch chunk
constexpr int ST     = 512;           // sort threads (8 waves)

typedef unsigned long long u64;

// ---------------- kernel 1: per-row stable argsort (hybrid bitonic) --------
// T=512: thread (wv,l) owns elements i0 = wv*128+l and i1 = i0+64.
// j<=32 stages: __shfl_xor (no barriers). j==64: intra-thread. j>=128: LDS.
__global__ __launch_bounds__(ST) void snn_sort_kernel(const float* __restrict__ x,
                                                      float* __restrict__ xs_g,
                                                      int* __restrict__ ro_g) {
    __shared__ u64 keys[NIN];
    const int tid = threadIdx.x;
    const int b   = blockIdx.x;
    const int wv  = tid >> 6;
    const int l   = tid & 63;
    const int i0  = wv * 128 + l;     // bit6 == 0 always
    const int i1  = i0 + 64;

    // key = (float_bits << 32) | index: x >= 0 so uint order == float order;
    // index low bits make keys distinct -> deterministic == stable argsort.
    u64 e0 = ((u64)__float_as_uint(x[b * NIN + i0]) << 32) | (unsigned)i0;
    u64 e1 = ((u64)__float_as_uint(x[b * NIN + i1]) << 32) | (unsigned)i1;

    auto CE_SHFL = [&](u64& e, int idx, int k, int j) {
        u64 p = __shfl_xor(e, j, 64);
        bool lower   = ((l & j) == 0);
        bool asc     = ((idx & k) == 0);
        bool takeMin = (lower == asc);
        bool pLess   = (p < e);
        e = (pLess == takeMin) ? p : e;
    };
    auto CE_J64 = [&](int k) {
        bool asc = ((i0 & k) == 0);
        bool sw  = asc ? (e0 > e1) : (e0 < e1);
        if (sw) { u64 t = e0; e0 = e1; e1 = t; }
    };

    for (int k = 2; k <= 64; k <<= 1)
        for (int j = k >> 1; j >= 1; j >>= 1) { CE_SHFL(e0, i0, k, j); CE_SHFL(e1, i1, k, j); }
    CE_J64(128);
    for (int j = 32; j >= 1; j >>= 1) { CE_SHFL(e0, i0, 128, j); CE_SHFL(e1, i1, 128, j); }

    for (int k = 256; k <= NIN; k <<= 1) {
        keys[i0] = e0; keys[i1] = e1;
        __syncthreads();
        for (int j = k >> 1; j >= 128; j >>= 1) {
            int idx  = ((tid & ~(j - 1)) << 1) | (tid & (j - 1));
            int part = idx | j;
            u64 a = keys[idx], c = keys[part];
            bool asc = ((idx & k) == 0);
            if (asc ? (a > c) : (a < c)) { keys[idx] = c; keys[part] = a; }
            __syncthreads();
        }
        e0 = keys[i0]; e1 = keys[i1];
        CE_J64(k);
        for (int j = 32; j >= 1; j >>= 1) { CE_SHFL(e0, i0, k, j); CE_SHFL(e1, i1, k, j); }
    }

    xs_g[b * (NIN + 1) + i0] = __uint_as_float((unsigned)(e0 >> 32));
    xs_g[b * (NIN + 1) + i1] = __uint_as_float((unsigned)(e1 >> 32));
    ro_g[b * NIN + i0] = (int)(unsigned)(e0 & 0xFFFFFFFFull) * (MOUT * 4);  // byte off
    ro_g[b * NIN + i1] = (int)(unsigned)(e1 & 0xFFFFFFFFull) * (MOUT * 4);
    if (tid == 0) xs_g[b * (NIN + 1) + NIN] = MAX_SPIKE;
}

// ---------------- kernel 2: 8-segment scan, screened division --------------
// Round-4 structure (proven 28 VGPR / 52 us at 4 waves) widened to 8 segments
// for 32 waves/CU; launch_bounds(512,8) pins VGPR <= 64 (the r6 regression
// was VGPR=80 -> wave cap 4/SIMD -> zero drain overlap).
__global__ __launch_bounds__(T, 8) void snn_scan_kernel(const float* __restrict__ w,
                                                        const float* __restrict__ xs_g,
                                                        const int* __restrict__ ro_g,
                                                        float* __restrict__ out) {
    // Running cumsums + exact path must match numpy f32: no FMA contraction.
    #pragma clang fp contract(off)

    __shared__ float xs[NIN + 1];
    __shared__ int   roff4[NIN];
    __shared__ float bestsh[NWAVE][CPB];

    const int tid  = threadIdx.x;
    const int b    = blockIdx.x >> 3;
    const int cg   = blockIdx.x & 7;
    const int wave = tid >> 6;
    const int lane = tid & 63;
    const int seg  = (wave + blockIdx.x) & (NWAVE - 1);   // straggler swizzle
    const unsigned mo4 = (unsigned)(cg * CPB + lane) * 4u;

    for (int i = tid; i < NIN + 1; i += T) xs[i] = xs_g[b * (NIN + 1) + i];
    for (int i = tid; i < NIN; i += T)     roff4[i] = ro_g[b * NIN + i];
    __syncthreads();

    const char* wb = (const char*)w;
    float wcum = 0.0f, wicum = 0.0f, best = MAX_SPIKE;
    float wA[CH], wB[CH];

#define LOADC(dst, base_) { const int bb_ = (base_); _Pragma("unroll") \
    for (int u = 0; u < CH; ++u) \
        dst[u] = *(const float*)(wb + ((unsigned)roff4[bb_ + u] + mo4)); }

    // ---- phase 1: exact sequential prefix over [0, seg*SEGLEN); no screens.
    const int npre = seg * SEGLEN;                 // 0..896, npre/CH even
    if (npre > 0) {
        LOADC(wA, 0);
        for (int c = 0; c < npre / CH; c += 2) {
            LOADC(wB, (c + 1) * CH);
            #pragma unroll
            for (int u = 0; u < CH; ++u) {
                float ww = wA[u];
                wcum  = wcum + ww;
                wicum = wicum + ww * xs[c * CH + u];   // round mul, then add
            }
            if ((c + 2) * CH < npre) LOADC(wA, (c + 2) * CH);
            #pragma unroll
            for (int u = 0; u < CH; ++u) {
                float ww = wB[u];
                wcum  = wcum + ww;
                wicum = wicum + ww * xs[(c + 1) * CH + u];
            }
        }
    }

    // ---- phase 2: candidate scan on own segment.
    // Cheap mode while ALL lanes have wcum < 1: weights >= 0 so wcum is
    // monotone; every element of such a chunk has wcum < 1 => reference emits
    // MAX_SPIKE exactly, no candidate possible. The chunk where any lane
    // crosses is REPLAYED from a 2-register snapshot in screen mode
    // (identical add order => bit-exact).
    // Screen skips only when the exact path provably rejects (1-ulp margins);
    // borderline lanes take the exact IEEE-division reference path.
    const int n0 = seg * SEGLEN;
    bool scr = (__any((int)(wcum >= 1.0f)) != 0);
    float xprev = xs[n0];

#define PROCESS(wreg, nb_) { const int nb = (nb_); \
    if (!scr) { \
        float wc0 = wcum, wi0 = wicum; \
        _Pragma("unroll") \
        for (int u = 0; u < CH; ++u) { \
            float ww = wreg[u]; \
            wcum  = wcum + ww; \
            wicum = wicum + ww * xs[nb + u]; \
        } \
        if (__any((int)(wcum >= 1.0f))) { \
            wcum = wc0; wicum = wi0; scr = true; xprev = xs[nb]; \
        } \
    } \
    if (scr) { \
        _Pragma("unroll") \
        for (int u = 0; u < CH; ++u) { \
            float ww = wreg[u]; \
            float xv = xprev; \
            float xl = xs[nb + u + 1]; \
            wcum  = wcum + ww; \
            wicum = wicum + ww * xv; \
            float d = fmaxf(wcum - 1.0f, 1e-10f); /* 1e10 clip never binds: wcum<=~4.3 */ \
            bool pot = (wcum >= 1.0f) && (wicum >= (xv * d) * (1.0f - 8e-7f)) \
                                      && (wicum <= (xl * d) * (1.0f + 8e-7f)); \
            if (pot) { \
                float q = wicum / d;            /* IEEE f32 div (matches np) */ \
                float cand = (q < xv || q > xl) ? MAX_SPIKE : q; \
                best = fminf(best, cand); \
            } \
            xprev = xl; \
        } \
    } }

    LOADC(wA, n0);
    constexpr int NCH2 = SEGLEN / CH;        // 16 (even)
    for (int c = 0; c < NCH2; c += 2) {
        LOADC(wB, n0 + (c + 1) * CH);
        PROCESS(wA, n0 + c * CH);
        if (c + 2 < NCH2) LOADC(wA, n0 + (c + 2) * CH);
        PROCESS(wB, n0 + (c + 1) * CH);
    }
#undef PROCESS
#undef LOADC

    bestsh[wave][lane] = best;
    __syncthreads();
    if (tid < CPB) {
        float r0 = fminf(fminf(fminf(bestsh[0][tid], bestsh[1][tid]),
                               fminf(bestsh[2][tid], bestsh[3][tid])),
                         fminf(fminf(bestsh[4][tid], bestsh[5][tid]),
                               fminf(bestsh[6][tid], bestsh[7][tid])));
        out[b * MOUT + cg * CPB + tid] = r0;
    }
}

// ---------------- fallback: fused kernel (if ws too small) -----------------
__global__ __launch_bounds__(256) void snn_fc_fused(const float* __restrict__ x,
                                                    const float* __restrict__ w,
                                                    float* __restrict__ out) {
    #pragma clang fp contract(off)
    __shared__ u64 keys[NIN];
    __shared__ float xs[NIN + 1];
    __shared__ int   roff[NIN];
    __shared__ float bestsh[4][CPB];

    const int tid  = threadIdx.x;
    const int b    = blockIdx.x >> 3;
    const int cg   = blockIdx.x & 7;
    const int wave = tid >> 6;
    const int lane = tid & 63;
    const int mo   = cg * CPB + lane;

    for (int i = tid; i < NIN; i += 256) {
        unsigned int bits = __float_as_uint(x[b * NIN + i]);
        keys[i] = ((u64)bits << 32) | (unsigned int)i;
    }
    __syncthreads();
    for (int k = 2; k <= NIN; k <<= 1)
        for (int j = k >> 1; j > 0; j >>= 1) {
            #pragma unroll
            for (int r = 0; r < NIN / 256; ++r) {
                int i = tid + r * 256, ixj = i ^ j;
                if (ixj > i) {
                    u64 a = keys[i], c2 = keys[ixj];
                    bool asc = ((i & k) == 0);
                    if ((a > c2) == asc) { keys[i] = c2; keys[ixj] = a; }
                }
            }
            __syncthreads();
        }
    for (int i = tid; i < NIN; i += 256) {
        u64 kk = keys[i];
        xs[i]   = __uint_as_float((unsigned int)(kk >> 32));
        roff[i] = (int)(kk & 0xFFFFFFFFull) * MOUT;
    }
    if (tid == 0) xs[NIN] = MAX_SPIKE;
    __syncthreads();

    const float* __restrict__ wcol = w + mo;
    float wcum = 0.0f, wicum = 0.0f, best = MAX_SPIKE;

    for (int n = 0; n < wave * 256; ++n) {
        float ww = wcol[roff[n]];
        wcum = wcum + ww;
        wicum = wicum + ww * xs[n];
    }
    const int n0 = wave * 256;
    float xprev = xs[n0];
    for (int n = n0; n < n0 + 256; ++n) {
        float ww = wcol[roff[n]];
        float xv = xprev, xl = xs[n + 1];
        wcum = wcum + ww;
        wicum = wicum + ww * xv;
        float d = fminf(fmaxf(wcum - 1.0f, 1e-10f), 1e10f);
        float q = wicum / d;
        float cand = (wcum < 1.0f || q < xv || q > xl) ? MAX_SPIKE : q;
        best = fminf(best, cand);
        xprev = xl;
    }
    bestsh[wave][lane] = best;
    __syncthreads();
    if (tid < CPB) {
        float r0 = fminf(fminf(bestsh[0][tid], bestsh[1][tid]),
                         fminf(bestsh[2][tid], bestsh[3][tid]));
        out[b * MOUT + cg * CPB + tid] = r0;
    }
}

extern "C" void kernel_launch(void* const* d_in, const int* in_sizes, int n_in,
                              void* d_out, int out_size, void* d_ws, size_t ws_size,
                              hipStream_t stream) {
    (void)in_sizes; (void)n_in; (void)out_size;
    const float* x = (const float*)d_in[0];
    const float* w = (const float*)d_in[1];
    float* out = (float*)d_out;

    const size_t xs_bytes = (size_t)BATCH * (NIN + 1) * sizeof(float);
    const size_t ro_bytes = (size_t)BATCH * NIN * sizeof(int);

    if (ws_size >= xs_bytes + ro_bytes) {
        float* xs_g = (float*)d_ws;
        int*   ro_g = (int*)((char*)d_ws + xs_bytes);
        hipLaunchKernelGGL(snn_sort_kernel, dim3(BATCH), dim3(ST), 0, stream,
                           x, xs_g, ro_g);
        hipLaunchKernelGGL(snn_scan_kernel, dim3(BATCH * (MOUT / CPB)), dim3(T),
                           0, stream, w, xs_g, ro_g, out);
    } else {
        hipLaunchKernelGGL(snn_fc_fused, dim3(BATCH * (MOUT / CPB)), dim3(256),
                           0, stream, x, w, out);
    }
}